// Round 11
// baseline (363.613 us; speedup 1.0000x reference)
//
#include <hip/hip_runtime.h>
#include <hip/hip_cooperative_groups.h>
#include <hip/hip_bf16.h>
#include <math.h>
#include <stdint.h>

namespace cg = cooperative_groups;

#define B_    2
#define S_    2048
#define HID_  768
#define NH_   12
#define HD_   64
#define NROWS (B_ * S_)                    // 4096
#define N_HID_ELEM (NROWS * HID_)          // 3145728
#define N_W_ELEM   (HID_ * HID_)           // 589824

#define KW   224
#define KSTR 232
#define MAX_BLKS 512
#define NTHR  256

typedef __bf16 bf16x8 __attribute__((ext_vector_type(8)));
typedef float  floatx4 __attribute__((ext_vector_type(4)));

__device__ __forceinline__ void gload_lds16(const __hip_bfloat16* g, __hip_bfloat16* l)
{
    __builtin_amdgcn_global_load_lds(
        (const __attribute__((address_space(1))) void*)g,
        (__attribute__((address_space(3))) void*)l, 16, 0, 0);
}

// ---------------------------------------------------------------------------
// fp32 -> bf16 convert body (grid-stride)
// ---------------------------------------------------------------------------
__device__ __forceinline__ void convert_body(
    int start, int stride,
    const float* __restrict__ hidden, const float* __restrict__ w1,
    const float* __restrict__ w2,
    __hip_bfloat16* __restrict__ Hb, __hip_bfloat16* __restrict__ Wqb,
    __hip_bfloat16* __restrict__ Wob)
{
    const int NH4 = N_HID_ELEM / 4, NW4 = N_W_ELEM / 4;
    const int TOT4 = NH4 + 2 * NW4;
    for (int i = start; i < TOT4; i += stride) {
        const float* src;
        __hip_bfloat16* dst;
        int off;
        if (i < NH4)            { src = hidden; dst = Hb;  off = i; }
        else if (i < NH4 + NW4) { src = w1;     dst = Wqb; off = i - NH4; }
        else                    { src = w2;     dst = Wob; off = i - NH4 - NW4; }
        float4 v = reinterpret_cast<const float4*>(src)[off];
        __hip_bfloat16 o[4] = { __float2bfloat16(v.x), __float2bfloat16(v.y),
                                __float2bfloat16(v.z), __float2bfloat16(v.w) };
        *reinterpret_cast<uint64_t*>(dst + 4 * (size_t)off) =
            *reinterpret_cast<uint64_t*>(o);
    }
}

// ---------------------------------------------------------------------------
// GEMM 64x64 tile (r7-verified body). smA/smW: [2][64][32] bf16 each (8 KB).
// ---------------------------------------------------------------------------
template<int ROPE>
__device__ __forceinline__ void gemm_tile(
    const __hip_bfloat16* __restrict__ A,
    const __hip_bfloat16* __restrict__ W,
    __hip_bfloat16* __restrict__ C, __hip_bfloat16* __restrict__ C2,
    float* __restrict__ Cf, const int* __restrict__ pos_idx,
    int m0, int n0, int K, int N,
    __hip_bfloat16* __restrict__ smA, __hip_bfloat16* __restrict__ smW)
{
    const int tid  = threadIdx.x;
    const int wv   = tid >> 6;
    const int lane = tid & 63;
    const int l16  = lane & 15;
    const int quad = lane >> 4;

    const int c   = wv * 64 + lane;
    const int sr  = c >> 2;
    const int sc8 = (c & 3) * 8;

    const __hip_bfloat16* gA = A + (size_t)(m0 + sr) * K + sc8;
    const __hip_bfloat16* gW = W + (size_t)(n0 + sr) * K + sc8;
    __hip_bfloat16* lA0 = smA + (wv * 16) * 32;
    __hip_bfloat16* lA1 = smA + 2048 + (wv * 16) * 32;
    __hip_bfloat16* lW0 = smW + (wv * 16) * 32;
    __hip_bfloat16* lW1 = smW + 2048 + (wv * 16) * 32;

    floatx4 acc[4] = {};
    const int ra = wv * 16 + l16;

    for (int k0 = 0; k0 < K; k0 += 64) {
        gload_lds16(gA + k0,      lA0);
        gload_lds16(gA + k0 + 32, lA1);
        gload_lds16(gW + k0,      lW0);
        gload_lds16(gW + k0 + 32, lW1);
        __syncthreads();
#pragma unroll
        for (int ks = 0; ks < 2; ++ks) {
            bf16x8 a = *reinterpret_cast<const bf16x8*>(&smA[ks * 2048 + ra * 32 + quad * 8]);
#pragma unroll
            for (int u = 0; u < 4; ++u) {
                bf16x8 w = *reinterpret_cast<const bf16x8*>(
                    &smW[ks * 2048 + (u * 16 + l16) * 32 + quad * 8]);
                acc[u] = __builtin_amdgcn_mfma_f32_16x16x32_bf16(a, w, acc[u], 0, 0, 0);
            }
        }
        __syncthreads();
    }

    if (ROPE) {
#pragma unroll
        for (int r = 0; r < 4; ++r) {
            int m = m0 + wv * 16 + quad * 4 + r;
            int s = m & (S_ - 1);
            float pos = (float)pos_idx[s];
#pragma unroll
            for (int u = 0; u < 2; ++u) {
                float f = (float)(u * 16 + l16);
                float inv = exp2f(f * (-0.41524101186092024f));
                float sn, cs;
                sincosf(pos * inv, &sn, &cs);
                float q0 = acc[u][r];
                float q1 = acc[u + 2][r];
                size_t base = (size_t)m * HID_ + n0 + u * 16 + l16;
                C [base]      = __float2bfloat16(q0);
                C [base + 32] = __float2bfloat16(q1);
                C2[base]      = __float2bfloat16(q0 * cs - q1 * sn);
                C2[base + 32] = __float2bfloat16(q1 * cs + q0 * sn);
            }
        }
    } else {
#pragma unroll
        for (int u = 0; u < 4; ++u)
#pragma unroll
            for (int r = 0; r < 4; ++r) {
                int row = m0 + wv * 16 + quad * 4 + r;
                int col = n0 + u * 16 + l16;
                Cf[(size_t)row * N + col] = acc[u][r];
            }
    }
}

// ---------------------------------------------------------------------------
// Banded attention tile (r9-verified body). VtB/PlB: 64*KSTR bf16 each.
// ---------------------------------------------------------------------------
__device__ __forceinline__ void attn_tile(
    const __hip_bfloat16* __restrict__ Q,
    const __hip_bfloat16* __restrict__ Qr,
    __hip_bfloat16* __restrict__ O,
    int b, int h, int i0,
    __hip_bfloat16* __restrict__ VtB, __hip_bfloat16* __restrict__ PlB)
{
    const int tid = threadIdx.x;

    for (int idx = tid; idx < KW * 8; idx += NTHR) {
        int w  = idx >> 3;
        int d8 = (idx & 7) * 8;
        int j  = i0 - 64 + w;
        int jc = min(max(j, 0), S_ - 1);
        bf16x8 v = *reinterpret_cast<const bf16x8*>(
            Q + ((size_t)(b * S_ + jc)) * HID_ + h * HD_ + d8);
        const __hip_bfloat16* ve = reinterpret_cast<const __hip_bfloat16*>(&v);
#pragma unroll
        for (int e = 0; e < 8; ++e) VtB[(d8 + e) * KSTR + w] = ve[e];
    }
    __syncthreads();

    const int wv   = tid >> 6;
    const int lane = tid & 63;
    const int l16  = lane & 15;
    const int quad = lane >> 4;

    floatx4 sc[10] = {};
    const __hip_bfloat16* qrow =
        Qr + ((size_t)(b * S_ + i0 + wv * 16 + l16)) * HID_ + h * HD_ + quad * 8;
#pragma unroll
    for (int ks = 0; ks < 2; ++ks) {
        bf16x8 a = *reinterpret_cast<const bf16x8*>(qrow + ks * 32);
#pragma unroll
        for (int t = 0; t < 10; ++t) {
            int j = i0 - 64 + (wv + t) * 16 + l16;
            int jc = min(max(j, 0), S_ - 1);
            bf16x8 bfr = *reinterpret_cast<const bf16x8*>(
                Qr + ((size_t)(b * S_ + jc)) * HID_ + h * HD_ + ks * 32 + quad * 8);
            sc[t] = __builtin_amdgcn_mfma_f32_16x16x32_bf16(a, bfr, sc[t], 0, 0, 0);
        }
    }

    const float scale = 0.125f;
    float denom[4];
#pragma unroll
    for (int r = 0; r < 4; ++r) {
        const int R = wv * 16 + quad * 4 + r;
        float xv[10];
        float mx = -3.0e38f;
#pragma unroll
        for (int t = 0; t < 10; ++t) {
            int w = (wv + t) * 16 + l16;
            int j = i0 - 64 + w;
            bool valid = (w >= R) && (w <= R + 128) && (j >= 0) && (j < S_);
            float x = valid ? sc[t][r] * scale : -1.0e30f;
            xv[t] = x;
            mx = fmaxf(mx, x);
        }
#pragma unroll
        for (int msk = 1; msk < 16; msk <<= 1) mx = fmaxf(mx, __shfl_xor(mx, msk, 64));
        float sum = 0.f;
#pragma unroll
        for (int t = 0; t < 10; ++t) {
            float p = __expf(xv[t] - mx);
            sum += p;
            PlB[R * KSTR + (wv + t) * 16 + l16] = __float2bfloat16(p);
        }
#pragma unroll
        for (int msk = 1; msk < 16; msk <<= 1) sum += __shfl_xor(sum, msk, 64);
        denom[r] = sum;
    }
    __syncthreads();

    floatx4 oacc[4] = {};
#pragma unroll
    for (int c = 0; c < 5; ++c) {
        const int base = wv * 16 + c * 32;
        bf16x8 a = *reinterpret_cast<const bf16x8*>(&PlB[(wv * 16 + l16) * KSTR + base + quad * 8]);
#pragma unroll
        for (int u = 0; u < 4; ++u) {
            bf16x8 bfr = *reinterpret_cast<const bf16x8*>(&VtB[(u * 16 + l16) * KSTR + base + quad * 8]);
            oacc[u] = __builtin_amdgcn_mfma_f32_16x16x32_bf16(a, bfr, oacc[u], 0, 0, 0);
        }
    }

    __syncthreads();
    float* Of = reinterpret_cast<float*>(PlB);   // [64][68] f32 = 17.4 KB
#pragma unroll
    for (int u = 0; u < 4; ++u)
#pragma unroll
        for (int r = 0; r < 4; ++r)
            Of[(wv * 16 + quad * 4 + r) * 68 + u * 16 + l16] = oacc[u][r] / denom[r];
    __syncthreads();
    {
        int row = tid >> 2;
        int seg = (tid & 3) * 16;
        __hip_bfloat16 ob[16];
#pragma unroll
        for (int e = 0; e < 16; ++e)
            ob[e] = __float2bfloat16(Of[row * 68 + seg + e]);
        __hip_bfloat16* dst = O + ((size_t)(b * S_ + i0 + row)) * HID_ + h * HD_ + seg;
        *reinterpret_cast<bf16x8*>(dst)     = *reinterpret_cast<bf16x8*>(ob);
        *reinterpret_cast<bf16x8*>(dst + 8) = *reinterpret_cast<bf16x8*>(ob + 8);
    }
    __syncthreads();
}

// ---------------------------------------------------------------------------
// Cooperative mega-kernel: convert -> gemm1+RoPE -> attn -> gemm2.
// Grid size chosen at launch from occupancy query; loops stride by gridDim.
// ---------------------------------------------------------------------------
__global__ __launch_bounds__(NTHR) void fused_all(
    const float* __restrict__ hidden, const float* __restrict__ w1,
    const float* __restrict__ w2, const int* __restrict__ pos,
    __hip_bfloat16* __restrict__ Hb, __hip_bfloat16* __restrict__ Wqb,
    __hip_bfloat16* __restrict__ Wob, __hip_bfloat16* __restrict__ Q,
    __hip_bfloat16* __restrict__ Qr, float* __restrict__ out)
{
    __shared__ __align__(16) unsigned char smraw[2 * 64 * KSTR * 2];  // 59392 B
    __hip_bfloat16* sm0 = reinterpret_cast<__hip_bfloat16*>(smraw);

    cg::grid_group grid = cg::this_grid();
    const int bid   = blockIdx.x;
    const int nblk  = gridDim.x;
    const int tid   = threadIdx.x;

    convert_body(bid * NTHR + tid, nblk * NTHR, hidden, w1, w2, Hb, Wqb, Wob);
    __threadfence();
    grid.sync();

    {   // gemm1 + RoPE
        __hip_bfloat16* smA = sm0;
        __hip_bfloat16* smW = sm0 + 4096;
        for (int job = bid; job < 64 * 12; job += nblk) {
            int m0 = (job & 63) * 64;
            int n0 = (job >> 6) * 64;
            gemm_tile<1>(Hb, Wqb, Q, Qr, nullptr, pos, m0, n0, HID_, HID_, smA, smW);
        }
    }
    __threadfence();
    grid.sync();

    {   // banded attention -> AO (aliases Hb)
        __hip_bfloat16* VtB = sm0;
        __hip_bfloat16* PlB = sm0 + 64 * KSTR;
        for (int job = bid; job < 32 * B_ * NH_; job += nblk) {
            int i0 = (job & 31) * 64;
            int bh = job >> 5;
            attn_tile(Q, Qr, Hb, bh / NH_, bh % NH_, i0, VtB, PlB);
        }
    }
    __threadfence();
    grid.sync();

    {   // gemm2 -> fp32 out
        __hip_bfloat16* smA = sm0;
        __hip_bfloat16* smW = sm0 + 4096;
        for (int job = bid; job < 64 * 12; job += nblk) {
            int m0 = (job & 63) * 64;
            int n0 = (job >> 6) * 64;
            gemm_tile<0>(Hb, Wob, nullptr, nullptr, out, nullptr, m0, n0, HID_, HID_, smA, smW);
        }
    }
}

// ---------------------------------------------------------------------------
// Fallback standalone kernels (r7/r9-passing structure, shared bodies).
// ---------------------------------------------------------------------------
__global__ __launch_bounds__(NTHR) void convert_sa(
    const float* __restrict__ hidden, const float* __restrict__ w1,
    const float* __restrict__ w2,
    __hip_bfloat16* __restrict__ Hb, __hip_bfloat16* __restrict__ Wqb,
    __hip_bfloat16* __restrict__ Wob)
{
    convert_body(blockIdx.x * NTHR + threadIdx.x, gridDim.x * NTHR,
                 hidden, w1, w2, Hb, Wqb, Wob);
}

template<int ROPE>
__global__ __launch_bounds__(NTHR) void gemm_sa(
    const __hip_bfloat16* __restrict__ A, const __hip_bfloat16* __restrict__ W,
    __hip_bfloat16* __restrict__ C, __hip_bfloat16* __restrict__ C2,
    float* __restrict__ Cf, const int* __restrict__ pos_idx)
{
    __shared__ __align__(16) __hip_bfloat16 smA[4096];
    __shared__ __align__(16) __hip_bfloat16 smW[4096];
    gemm_tile<ROPE>(A, W, C, C2, Cf, pos_idx,
                    blockIdx.x * 64, blockIdx.y * 64, HID_, HID_, smA, smW);
}

__global__ __launch_bounds__(NTHR) void attn_sa(
    const __hip_bfloat16* __restrict__ Q, const __hip_bfloat16* __restrict__ Qr,
    __hip_bfloat16* __restrict__ O)
{
    __shared__ __align__(16) __hip_bfloat16 VtB[64 * KSTR];
    __shared__ __align__(16) __hip_bfloat16 PlB[64 * KSTR];
    int bh = blockIdx.y;
    attn_tile(Q, Qr, O, bh / NH_, bh % NH_, blockIdx.x * 64, VtB, PlB);
}

// ---------------------------------------------------------------------------
extern "C" void kernel_launch(void* const* d_in, const int* in_sizes, int n_in,
                              void* d_out, int out_size, void* d_ws, size_t ws_size,
                              hipStream_t stream)
{
    int ih = -1, iw1 = -1, iw2 = -1, ip = -1;
    for (int i = 0; i < n_in; ++i) {
        int s = in_sizes[i];
        if      (s == N_HID_ELEM && ih < 0) ih = i;
        else if (s == N_W_ELEM)  { if (iw1 < 0) iw1 = i; else if (iw2 < 0) iw2 = i; }
        else if (s == S_ && ip < 0) ip = i;
    }
    if (ih < 0)  ih = 0;
    if (iw1 < 0) iw1 = 1;
    if (iw2 < 0) iw2 = 2;
    if (ip < 0)  ip = 5;

    const float* hidden = (const float*)d_in[ih];
    const float* w1     = (const float*)d_in[iw1];
    const float* w2     = (const float*)d_in[iw2];
    const int*   pos    = (const int*)d_in[ip];

    __hip_bfloat16* Hb  = (__hip_bfloat16*)d_ws;
    __hip_bfloat16* Wqb = Hb  + N_HID_ELEM;
    __hip_bfloat16* Wob = Wqb + N_W_ELEM;
    __hip_bfloat16* Q   = Wob + N_W_ELEM;
    __hip_bfloat16* Qr  = Q   + N_HID_ELEM;
    float* out          = (float*)d_out;

    // ---- try cooperative fused path with occupancy-derived grid ----
    bool launched = false;
    int maxPerCU = 0;
    hipError_t oe = hipOccupancyMaxActiveBlocksPerMultiprocessor(
        &maxPerCU, (const void*)fused_all, NTHR, 0);
    if (oe == hipSuccess && maxPerCU > 0) {
        int nblk = maxPerCU * 256;          // 256 CUs on MI355X
        if (nblk > MAX_BLKS) nblk = MAX_BLKS;
        void* args[] = { (void*)&hidden, (void*)&w1, (void*)&w2, (void*)&pos,
                         (void*)&Hb, (void*)&Wqb, (void*)&Wob, (void*)&Q,
                         (void*)&Qr, (void*)&out };
        hipError_t le = hipLaunchCooperativeKernel(
            (const void*)fused_all, dim3(nblk), dim3(NTHR), args, 0, stream);
        launched = (le == hipSuccess);
    }

    // ---- deterministic fallback: 4-dispatch r7/r9 path ----
    if (!launched) {
        const int NH4 = N_HID_ELEM / 4, NW4 = N_W_ELEM / 4;
        int conv4 = NH4 + 2 * NW4;
        convert_sa<<<(conv4 + NTHR - 1) / NTHR, NTHR, 0, stream>>>(
            hidden, w1, w2, Hb, Wqb, Wob);
        dim3 gblk(NROWS / 64, HID_ / 64);
        gemm_sa<1><<<gblk, NTHR, 0, stream>>>(Hb, Wqb, Q, Qr, nullptr, pos);
        attn_sa<<<dim3(S_ / 64, B_ * NH_), NTHR, 0, stream>>>(Q, Qr, Hb);
        gemm_sa<0><<<gblk, NTHR, 0, stream>>>(Hb, Wob, nullptr, nullptr, out, nullptr);
    }
}

// Round 12
// 144.237 us; speedup vs baseline: 2.5209x; 2.5209x over previous
//
#include <hip/hip_runtime.h>
#include <hip/hip_bf16.h>
#include <math.h>
#include <stdint.h>

#define B_    2
#define S_    2048
#define HID_  768
#define NH_   12
#define HD_   64
#define NROWS (B_ * S_)                    // 4096
#define N_HID_ELEM (NROWS * HID_)          // 3145728
#define N_W_ELEM   (HID_ * HID_)           // 589824

// attention LDS geometry: 224 staged keys, row stride 232
#define KW   224
#define KSTR 232

typedef __bf16 bf16x8 __attribute__((ext_vector_type(8)));
typedef float  floatx4 __attribute__((ext_vector_type(4)));

// fp32 -> bf16 conversion of hidden + Wq + Wo, x4 vectorized (r9-passing)
__global__ void convert_inputs_kernel(const float* __restrict__ src_hidden,
                                      const float* __restrict__ src_w1,
                                      const float* __restrict__ src_w2,
                                      __hip_bfloat16* __restrict__ Hb,
                                      __hip_bfloat16* __restrict__ Wqb,
                                      __hip_bfloat16* __restrict__ Wob)
{
    int i = blockIdx.x * blockDim.x + threadIdx.x;   // float4 index
    const float* src;
    __hip_bfloat16* dst;
    int off;
    const int NH4 = N_HID_ELEM / 4, NW4 = N_W_ELEM / 4;
    if (i < NH4)           { src = src_hidden; dst = Hb;  off = i; }
    else if (i < NH4+NW4)  { src = src_w1;     dst = Wqb; off = i - NH4; }
    else if (i < NH4+2*NW4){ src = src_w2;     dst = Wob; off = i - NH4 - NW4; }
    else return;
    float4 v = reinterpret_cast<const float4*>(src)[off];
    __hip_bfloat16 o[4] = { __float2bfloat16(v.x), __float2bfloat16(v.y),
                            __float2bfloat16(v.z), __float2bfloat16(v.w) };
    *reinterpret_cast<uint64_t*>(dst + 4 * (size_t)off) = *reinterpret_cast<uint64_t*>(o);
}

__device__ __forceinline__ void gload_lds16(const __hip_bfloat16* g, __hip_bfloat16* l)
{
    __builtin_amdgcn_global_load_lds(
        (const __attribute__((address_space(1))) void*)g,
        (__attribute__((address_space(3))) void*)l, 16, 0, 0);
}

// ---------------------------------------------------------------------------
// 32x64-tile GEMM: C[m][n] = sum_k A[m][k]*W[n][k]. BK=64 (two 32-halves),
// 128 threads (2 waves). Grid (M/32, N/64) = (128,12) = 1536 blocks
// -> ~6 co-resident blocks/CU (12 KB LDS) = 2x the independent K-chains of
// the 64-tile version. Staging: m97 lane-contiguous per-half glds.
// Wave wv computes rows [wv*16, wv*16+16) x 64 cols (4 accs).
// ROPE=1: epilogue writes Q,Qr (bf16).  ROPE=0: writes fp32 Cf.
// ---------------------------------------------------------------------------
template<int ROPE>
__global__ __launch_bounds__(128) void gemm32(
    const __hip_bfloat16* __restrict__ A,
    const __hip_bfloat16* __restrict__ W,
    __hip_bfloat16* __restrict__ C,        // ROPE: Q
    __hip_bfloat16* __restrict__ C2,       // ROPE: Qr
    float* __restrict__ Cf,                // !ROPE
    const int* __restrict__ pos_idx,
    int M, int N, int K)
{
    __shared__ __align__(16) __hip_bfloat16 Ald[2][32][32];   // 4 KB
    __shared__ __align__(16) __hip_bfloat16 Wld[2][64][32];   // 8 KB

    const int tid  = threadIdx.x;
    const int wv   = tid >> 6;             // 0/1
    const int lane = tid & 63;
    const int l16  = lane & 15;
    const int quad = lane >> 4;
    const int m0 = blockIdx.x * 32;
    const int n0 = blockIdx.y * 64;

    // staging: 16B chunk c -> row = c>>2, col8 = (c&3)*8 (within a 32-k half)
    const int sr  = tid >> 2;              // 0..31
    const int sc8 = (tid & 3) * 8;

    // A: per half 128 chunks = 1 issue/wave (chunk = tid)
    const __hip_bfloat16* gA0 = A + (size_t)(m0 + sr) * K + sc8;        // half0
    const __hip_bfloat16* gA1 = A + (size_t)(m0 + sr) * K + 32 + sc8;   // half1
    // W: per half 256 chunks = 2 issues/wave (chunks tid, tid+128)
    const __hip_bfloat16* gW0a = W + (size_t)(n0 + sr) * K + sc8;
    const __hip_bfloat16* gW0b = W + (size_t)(n0 + 32 + sr) * K + sc8;
    const __hip_bfloat16* gW1a = W + (size_t)(n0 + sr) * K + 32 + sc8;
    const __hip_bfloat16* gW1b = W + (size_t)(n0 + 32 + sr) * K + 32 + sc8;

    __hip_bfloat16* lA0  = &Ald[0][wv * 16][0];        // wave-uniform bases
    __hip_bfloat16* lA1  = &Ald[1][wv * 16][0];
    __hip_bfloat16* lW0a = &Wld[0][wv * 16][0];
    __hip_bfloat16* lW0b = &Wld[0][32 + wv * 16][0];
    __hip_bfloat16* lW1a = &Wld[1][wv * 16][0];
    __hip_bfloat16* lW1b = &Wld[1][32 + wv * 16][0];

    floatx4 acc[4] = {};
    const int ra = wv * 16 + l16;          // A-fragment row (0..31)

    for (int k0 = 0; k0 < K; k0 += 64) {
        gload_lds16(gA0  + k0, lA0);
        gload_lds16(gA1  + k0, lA1);
        gload_lds16(gW0a + k0, lW0a);
        gload_lds16(gW0b + k0, lW0b);
        gload_lds16(gW1a + k0, lW1a);
        gload_lds16(gW1b + k0, lW1b);
        __syncthreads();

#pragma unroll
        for (int ks = 0; ks < 2; ++ks) {
            bf16x8 a = *reinterpret_cast<const bf16x8*>(&Ald[ks][ra][quad * 8]);
#pragma unroll
            for (int u = 0; u < 4; ++u) {
                bf16x8 w = *reinterpret_cast<const bf16x8*>(&Wld[ks][u * 16 + l16][quad * 8]);
                acc[u] = __builtin_amdgcn_mfma_f32_16x16x32_bf16(a, w, acc[u], 0, 0, 0);
            }
        }
        __syncthreads();
    }

    // epilogue: D row = m0 + wv*16 + quad*4 + r, col = n0 + u*16 + l16
    if (ROPE) {
#pragma unroll
        for (int r = 0; r < 4; ++r) {
            int m = m0 + wv * 16 + quad * 4 + r;
            int s = m & (S_ - 1);
            float pos = (float)pos_idx[s];
#pragma unroll
            for (int u = 0; u < 2; ++u) {
                float f = (float)(u * 16 + l16);                 // 0..31
                float inv = exp2f(f * (-0.41524101186092024f)); // -log2(1e4)/32
                float sn, cs;
                sincosf(pos * inv, &sn, &cs);
                float q0 = acc[u][r];
                float q1 = acc[u + 2][r];
                size_t base = (size_t)m * HID_ + n0 + u * 16 + l16;
                C [base]      = __float2bfloat16(q0);
                C [base + 32] = __float2bfloat16(q1);
                C2[base]      = __float2bfloat16(q0 * cs - q1 * sn);
                C2[base + 32] = __float2bfloat16(q1 * cs + q0 * sn);
            }
        }
    } else {
#pragma unroll
        for (int u = 0; u < 4; ++u)
#pragma unroll
            for (int r = 0; r < 4; ++r) {
                int row = m0 + wv * 16 + quad * 4 + r;
                int col = n0 + u * 16 + l16;
                Cf[(size_t)row * N + col] = acc[u][r];
            }
    }
}

// ---------------------------------------------------------------------------
// Banded attention (r9-passing body, unchanged).
// ---------------------------------------------------------------------------
__global__ __launch_bounds__(256) void attn_kernel(
    const __hip_bfloat16* __restrict__ Q,    // pre-rope  (= V)
    const __hip_bfloat16* __restrict__ Qr,   // post-rope (= Q = K)
    __hip_bfloat16* __restrict__ O)
{
    __shared__ __align__(16) __hip_bfloat16 Vt[64][KSTR];   // [dim][window]
    __shared__ __align__(16) __hip_bfloat16 Pl[64][KSTR];   // [row][window]

    const int bh = blockIdx.y;
    const int b  = bh / NH_;
    const int h  = bh % NH_;
    const int i0 = blockIdx.x * 64;
    const int tid = threadIdx.x;

    for (int idx = tid; idx < KW * 8; idx += 256) {
        int w  = idx >> 3;
        int d8 = (idx & 7) * 8;
        int j  = i0 - 64 + w;
        int jc = min(max(j, 0), S_ - 1);
        bf16x8 v = *reinterpret_cast<const bf16x8*>(
            Q + ((size_t)(b * S_ + jc)) * HID_ + h * HD_ + d8);
        const __hip_bfloat16* ve = reinterpret_cast<const __hip_bfloat16*>(&v);
#pragma unroll
        for (int e = 0; e < 8; ++e) Vt[d8 + e][w] = ve[e];
    }
    __syncthreads();

    const int wv   = tid >> 6;
    const int lane = tid & 63;
    const int l16  = lane & 15;
    const int quad = lane >> 4;

    floatx4 sc[10] = {};
    const __hip_bfloat16* qrow =
        Qr + ((size_t)(b * S_ + i0 + wv * 16 + l16)) * HID_ + h * HD_ + quad * 8;
#pragma unroll
    for (int ks = 0; ks < 2; ++ks) {
        bf16x8 a = *reinterpret_cast<const bf16x8*>(qrow + ks * 32);
#pragma unroll
        for (int t = 0; t < 10; ++t) {
            int j = i0 - 64 + (wv + t) * 16 + l16;
            int jc = min(max(j, 0), S_ - 1);
            bf16x8 bfr = *reinterpret_cast<const bf16x8*>(
                Qr + ((size_t)(b * S_ + jc)) * HID_ + h * HD_ + ks * 32 + quad * 8);
            sc[t] = __builtin_amdgcn_mfma_f32_16x16x32_bf16(a, bfr, sc[t], 0, 0, 0);
        }
    }

    const float scale = 0.125f;
    float denom[4];
#pragma unroll
    for (int r = 0; r < 4; ++r) {
        const int R = wv * 16 + quad * 4 + r;
        float xv[10];
        float mx = -3.0e38f;
#pragma unroll
        for (int t = 0; t < 10; ++t) {
            int w = (wv + t) * 16 + l16;
            int j = i0 - 64 + w;
            bool valid = (w >= R) && (w <= R + 128) && (j >= 0) && (j < S_);
            float x = valid ? sc[t][r] * scale : -1.0e30f;
            xv[t] = x;
            mx = fmaxf(mx, x);
        }
#pragma unroll
        for (int msk = 1; msk < 16; msk <<= 1) mx = fmaxf(mx, __shfl_xor(mx, msk, 64));
        float sum = 0.f;
#pragma unroll
        for (int t = 0; t < 10; ++t) {
            float p = __expf(xv[t] - mx);
            sum += p;
            Pl[R][(wv + t) * 16 + l16] = __float2bfloat16(p);
        }
#pragma unroll
        for (int msk = 1; msk < 16; msk <<= 1) sum += __shfl_xor(sum, msk, 64);
        denom[r] = sum;
    }
    __syncthreads();

    floatx4 oacc[4] = {};
#pragma unroll
    for (int c = 0; c < 5; ++c) {
        const int base = wv * 16 + c * 32;
        bf16x8 a = *reinterpret_cast<const bf16x8*>(&Pl[wv * 16 + l16][base + quad * 8]);
#pragma unroll
        for (int u = 0; u < 4; ++u) {
            bf16x8 bfr = *reinterpret_cast<const bf16x8*>(&Vt[u * 16 + l16][base + quad * 8]);
            oacc[u] = __builtin_amdgcn_mfma_f32_16x16x32_bf16(a, bfr, oacc[u], 0, 0, 0);
        }
    }

    __syncthreads();
    float* Of = reinterpret_cast<float*>(&Pl[0][0]);   // [64][68] f32
#pragma unroll
    for (int u = 0; u < 4; ++u)
#pragma unroll
        for (int r = 0; r < 4; ++r)
            Of[(wv * 16 + quad * 4 + r) * 68 + u * 16 + l16] = oacc[u][r] / denom[r];
    __syncthreads();
    {
        int row = tid >> 2;
        int seg = (tid & 3) * 16;
        __hip_bfloat16 ob[16];
#pragma unroll
        for (int e = 0; e < 16; ++e)
            ob[e] = __float2bfloat16(Of[row * 68 + seg + e]);
        __hip_bfloat16* dst = O + ((size_t)(b * S_ + i0 + row)) * HID_ + h * HD_ + seg;
        *reinterpret_cast<bf16x8*>(dst)     = *reinterpret_cast<bf16x8*>(ob);
        *reinterpret_cast<bf16x8*>(dst + 8) = *reinterpret_cast<bf16x8*>(ob + 8);
    }
}

// ---------------------------------------------------------------------------
extern "C" void kernel_launch(void* const* d_in, const int* in_sizes, int n_in,
                              void* d_out, int out_size, void* d_ws, size_t ws_size,
                              hipStream_t stream)
{
    int ih = -1, iw1 = -1, iw2 = -1, ip = -1;
    for (int i = 0; i < n_in; ++i) {
        int s = in_sizes[i];
        if      (s == N_HID_ELEM && ih < 0) ih = i;
        else if (s == N_W_ELEM)  { if (iw1 < 0) iw1 = i; else if (iw2 < 0) iw2 = i; }
        else if (s == S_ && ip < 0) ip = i;
    }
    if (ih < 0)  ih = 0;
    if (iw1 < 0) iw1 = 1;
    if (iw2 < 0) iw2 = 2;
    if (ip < 0)  ip = 5;

    const float* hidden = (const float*)d_in[ih];
    const float* w1     = (const float*)d_in[iw1];
    const float* w2     = (const float*)d_in[iw2];
    const int*   pos    = (const int*)d_in[ip];

    __hip_bfloat16* Hb  = (__hip_bfloat16*)d_ws;
    __hip_bfloat16* Wqb = Hb  + N_HID_ELEM;
    __hip_bfloat16* Wob = Wqb + N_W_ELEM;
    __hip_bfloat16* Q   = Wob + N_W_ELEM;
    __hip_bfloat16* Qr  = Q   + N_HID_ELEM;
    __hip_bfloat16* AO  = Hb;   // Hb dead after gemm1

    int conv4 = (N_HID_ELEM + 2 * N_W_ELEM) / 4;
    convert_inputs_kernel<<<(conv4 + 255) / 256, 256, 0, stream>>>(
        hidden, w1, w2, Hb, Wqb, Wob);

    dim3 gblk(NROWS / 32, HID_ / 64);   // (128, 12) = 1536 blocks

    // GEMM1 + fused RoPE -> Q, Qr
    gemm32<1><<<gblk, 128, 0, stream>>>(Hb, Wqb, Q, Qr, nullptr, pos,
                                        NROWS, HID_, HID_);

    attn_kernel<<<dim3(S_ / 64, B_ * NH_), 256, 0, stream>>>(Q, Qr, AO);

    // GEMM2 -> fp32 out
    gemm32<0><<<gblk, 128, 0, stream>>>(AO, Wob, nullptr, nullptr, (float*)d_out,
                                        nullptr, NROWS, HID_, HID_);
}